// Round 2
// baseline (20508.722 us; speedup 1.0000x reference)
//
#include <hip/hip_runtime.h>
#include <hip/hip_bf16.h>

#define B_ 64
#define T_ 512
#define O_ 512
#define N_ 2048
#define NWG 128
#define EPSF 1e-5f

typedef __attribute__((ext_vector_type(8))) short short8v;
typedef __attribute__((ext_vector_type(4))) float f32x4;
typedef unsigned short u16;

__device__ __forceinline__ u16 f2bf(float f) {
    union { float f; unsigned u; } v; v.f = f;
    unsigned r = v.u + 0x7fffu + ((v.u >> 16) & 1u);   // RNE
    return (u16)(r >> 16);
}

// ---------- init: W (fp32 [1024][2048]) -> wt bf16 [2048 col][1024 k] ----------
__global__ void k_init_wt(const float* __restrict__ W, u16* __restrict__ wt) {
    int n = blockIdx.x;
    for (int k = threadIdx.x; k < 1024; k += 256)
        wt[(size_t)n * 1024 + k] = f2bf(W[(size_t)k * N_ + n]);
}

// ---------- init: x fp32 [b][t][k] -> xbf bf16 [t][b][k] ----------
__global__ void k_init_x(const float* __restrict__ x, u16* __restrict__ xbf) {
    size_t e = ((size_t)blockIdx.x * 256 + threadIdx.x) * 8;   // 0..16M
    int b = (int)(e >> 18);
    int r = (int)(e & 262143);
    int t = r >> 9, k = r & 511;
    float4 u0 = *(const float4*)(x + e);
    float4 u1 = *(const float4*)(x + e + 4);
    short8v v;
    v[0] = (short)f2bf(u0.x); v[1] = (short)f2bf(u0.y);
    v[2] = (short)f2bf(u0.z); v[3] = (short)f2bf(u0.w);
    v[4] = (short)f2bf(u1.x); v[5] = (short)f2bf(u1.y);
    v[6] = (short)f2bf(u1.z); v[7] = (short)f2bf(u1.w);
    *(short8v*)(xbf + ((size_t)t * B_ + b) * 512 + k) = v;
}

__global__ void k_zero_flags(unsigned* flags) {
    if (threadIdx.x < NWG) flags[threadIdx.x] = 0;
}

// ---------- grid barrier: flag array, monotonic generation ----------
__device__ __forceinline__ void gbar(unsigned* flags, int wgid, unsigned gen) {
    __syncthreads();
    if (threadIdx.x == 0) {
        __threadfence();   // wb dirty L2 (agent scope) before signaling
        __hip_atomic_store(flags + wgid, gen, __ATOMIC_RELEASE, __HIP_MEMORY_SCOPE_AGENT);
    }
    if (threadIdx.x < NWG) {
        while (__hip_atomic_load(flags + threadIdx.x, __ATOMIC_ACQUIRE,
                                 __HIP_MEMORY_SCOPE_AGENT) < gen) {}
    }
    __threadfence();       // invalidate L1/L2 so post-barrier reads are fresh
    __syncthreads();
}

// ---------- persistent LN-LSTM kernel ----------
template<bool XBF>
__global__ __launch_bounds__(256, 1)
void k_persist(const float* __restrict__ x, const u16* __restrict__ xbf,
               const u16* __restrict__ wt, const float* __restrict__ bias,
               const float* __restrict__ lnw, const float* __restrict__ lnb,
               const float* __restrict__ hx, const float* __restrict__ cx,
               u16* __restrict__ hbf, float* __restrict__ comb,
               float2* __restrict__ statsp, unsigned* __restrict__ flags,
               float* __restrict__ out) {
    __shared__ char wlds[32768];    // 16 cols x 1024 k bf16, XOR-swizzled by col
    __shared__ float sred[4];

    const int tid = threadIdx.x, wgid = blockIdx.x;
    const int n0 = wgid * 16;
    const int w = tid >> 6, l = tid & 63;
    const int rl = l & 15, kg = l >> 4;
    const int row = 16 * w + rl;          // batch row this lane's A-frag covers
    const int row0 = 16 * w + kg * 4;     // first C row this lane's acc covers

    // ---- load W slice into LDS (once) ----
    for (int it = 0; it < 8; ++it) {
        int idx = tid + 256 * it;         // 0..2047 16B-chunks
        int col = idx >> 7, k0 = (idx & 127) * 8;
        short8v v = *(const short8v*)(wt + (size_t)(n0 + col) * 1024 + k0);
        *(short8v*)(wlds + col * 2048 + ((k0 * 2) ^ ((col & 7) << 4))) = v;
    }

    // ---- phase-2 identity: wg -> (batch row b2, o-half); c lives in a register ----
    const int b2 = wgid >> 1;
    const int o = (wgid & 1) * 256 + tid;
    float lw0 = lnw[o], lw1 = lnw[512 + o], lw2 = lnw[1024 + o], lw3 = lnw[1536 + o];
    float lb0 = lnb[o], lb1 = lnb[512 + o], lb2 = lnb[1024 + o], lb3 = lnb[1536 + o];
    float creg = cx[o];
    hbf[b2 * O_ + o] = f2bf(hx[o]);
    const float bcol = bias[n0 + rl];

    unsigned gen = 1;
    gbar(flags, wgid, gen); gen++;        // hbf init + wlds visible

    for (int t = 0; t < T_; ++t) {
        // ================= phase 1: GEMM (64 rows x 16 cols, K=1024) =================
        f32x4 acc0 = {0.f, 0.f, 0.f, 0.f}, acc1 = {0.f, 0.f, 0.f, 0.f};
        const u16* hrow = hbf + row * O_;
        const u16* xrowb = XBF ? (xbf + ((size_t)t * B_ + row) * 512) : (const u16*)0;
        const float* xrowf = XBF ? (const float*)0 : (x + (size_t)row * (T_ * 512) + (size_t)t * 512);
#pragma unroll
        for (int kc = 0; kc < 32; ++kc) {
            int kloc = kc * 32 + kg * 8;  // 0..1023
            short8v a;
            if (kc < 16) {
                if (XBF) {
                    a = *(const short8v*)(xrowb + kloc);
                } else {
                    float4 u0 = *(const float4*)(xrowf + kloc);
                    float4 u1 = *(const float4*)(xrowf + kloc + 4);
                    a[0] = (short)f2bf(u0.x); a[1] = (short)f2bf(u0.y);
                    a[2] = (short)f2bf(u0.z); a[3] = (short)f2bf(u0.w);
                    a[4] = (short)f2bf(u1.x); a[5] = (short)f2bf(u1.y);
                    a[6] = (short)f2bf(u1.z); a[7] = (short)f2bf(u1.w);
                }
            } else {
                a = *(const short8v*)(hrow + (kloc - 512));
            }
            short8v bb = *(const short8v*)(wlds + rl * 2048 + (((kloc * 2)) ^ ((rl & 7) << 4)));
            if (kc & 1) acc1 = __builtin_amdgcn_mfma_f32_16x16x32_bf16(a, bb, acc1, 0, 0, 0);
            else        acc0 = __builtin_amdgcn_mfma_f32_16x16x32_bf16(a, bb, acc0, 0, 0, 0);
        }
        f32x4 acc = acc0 + acc1;

        // epilogue: +bias, store comb, per-row LN partials (sum over this wg's 16 cols)
        float sj[4], qj[4];
#pragma unroll
        for (int j = 0; j < 4; ++j) {
            float v = acc[j] + bcol;
            comb[(size_t)(row0 + j) * N_ + (n0 + rl)] = v;
            sj[j] = v; qj[j] = v * v;
        }
#pragma unroll
        for (int m = 1; m < 16; m <<= 1) {
#pragma unroll
            for (int j = 0; j < 4; ++j) {
                sj[j] += __shfl_xor(sj[j], m);
                qj[j] += __shfl_xor(qj[j], m);
            }
        }
        if (rl == 0) {
#pragma unroll
            for (int j = 0; j < 4; ++j)
                statsp[(size_t)(row0 + j) * NWG + wgid] = make_float2(sj[j], qj[j]);
        }

        gbar(flags, wgid, gen); gen++;    // comb + stats partials visible

        // ================= phase 2: LN + gates + state update =================
        float s = 0.f, q = 0.f;
        if (tid < NWG) {
            float2 p = statsp[(size_t)b2 * NWG + tid];
            s = p.x; q = p.y;
        }
#pragma unroll
        for (int m = 32; m > 0; m >>= 1) {
            s += __shfl_down(s, m);
            q += __shfl_down(q, m);
        }
        if (tid < NWG && (tid & 63) == 0) {
            sred[(tid >> 6) * 2] = s;
            sred[(tid >> 6) * 2 + 1] = q;
        }
        __syncthreads();
        float S = sred[0] + sred[2], Q = sred[1] + sred[3];
        float mu = S * (1.0f / 2048.0f);
        float var = Q * (1.0f / 2048.0f) - mu * mu;
        float rstd = rsqrtf(var + EPSF);

        const float* cb = comb + (size_t)b2 * N_ + o;
        float n0v = (cb[0]    - mu) * rstd * lw0 + lb0;
        float n1v = (cb[512]  - mu) * rstd * lw1 + lb1;
        float n2v = (cb[1024] - mu) * rstd * lw2 + lb2;
        float n3v = (cb[1536] - mu) * rstd * lw3 + lb3;
        float ig = 1.f / (1.f + __expf(-n0v));
        float fg = 1.f / (1.f + __expf(-n1v));
        float og = 1.f / (1.f + __expf(-n2v));
        float e2 = __expf(-2.f * fabsf(n3v));
        float th = copysignf((1.f - e2) / (1.f + e2), n3v);
        creg = fg * creg + ig * th;
        float h = og * creg;
        out[(size_t)b2 * (T_ * O_) + (size_t)t * O_ + o] = h;
        hbf[b2 * O_ + o] = f2bf(h);

        gbar(flags, wgid, gen); gen++;    // h visible for next step's GEMM
    }
}

extern "C" void kernel_launch(void* const* d_in, const int* in_sizes, int n_in,
                              void* d_out, int out_size, void* d_ws, size_t ws_size,
                              hipStream_t stream) {
    const float* x    = (const float*)d_in[0];
    const float* W    = (const float*)d_in[1];
    const float* bias = (const float*)d_in[2];
    const float* lnw  = (const float*)d_in[3];
    const float* lnb  = (const float*)d_in[4];
    const float* hx   = (const float*)d_in[5];
    const float* cx   = (const float*)d_in[6];
    float* out = (float*)d_out;

    char* ws = (char*)d_ws;
    u16*     wt     = (u16*)ws;                        // 4 MiB
    u16*     hbf    = (u16*)(ws + 4194304);            // 64 KiB
    float*   comb   = (float*)(ws + 4259840);          // 512 KiB
    float2*  statsp = (float2*)(ws + 4784128);         // 64 KiB
    unsigned* flags = (unsigned*)(ws + 4849664);       // 512 B
    u16*     xbf    = (u16*)(ws + 5242880);            // 32 MiB (optional)
    bool use_xbf = ws_size >= (5242880u + 33554432u);

    k_init_wt<<<2048, 256, 0, stream>>>(W, wt);
    k_zero_flags<<<1, 128, 0, stream>>>(flags);
    if (use_xbf) {
        k_init_x<<<8192, 256, 0, stream>>>(x, xbf);
        k_persist<true><<<NWG, 256, 0, stream>>>(x, xbf, wt, bias, lnw, lnb, hx, cx,
                                                 hbf, comb, statsp, flags, out);
    } else {
        k_persist<false><<<NWG, 256, 0, stream>>>(x, xbf, wt, bias, lnw, lnb, hx, cx,
                                                  hbf, comb, statsp, flags, out);
    }
}

// Round 3
// 9793.280 us; speedup vs baseline: 2.0942x; 2.0942x over previous
//
#include <hip/hip_runtime.h>
#include <hip/hip_bf16.h>

#define B_ 64
#define T_ 512
#define O_ 512
#define N_ 2048
#define NWG 128
#define EPSF 1e-5f

typedef __attribute__((ext_vector_type(8))) short short8v;
typedef __attribute__((ext_vector_type(4))) float f32x4;
typedef unsigned short u16;

__device__ __forceinline__ u16 f2bf(float f) {
    union { float f; unsigned u; } v; v.f = f;
    unsigned r = v.u + 0x7fffu + ((v.u >> 16) & 1u);   // RNE
    return (u16)(r >> 16);
}

// ---------- init: W fp32 [1024][2048] -> wt bf16 [2048 col][1024 k], LDS-tiled ----------
__global__ void k_init_wt(const float* __restrict__ W, u16* __restrict__ wt) {
    __shared__ u16 tile[64][65];              // pad -> worst 2-way bank conflict (free)
    const int tk = (blockIdx.x >> 5) * 64;    // k-tile (16)
    const int tn = (blockIdx.x & 31) * 64;    // n-tile (32)
    const int r = threadIdx.x >> 6, c = threadIdx.x & 63;
#pragma unroll
    for (int i = 0; i < 16; ++i)
        tile[r + 4 * i][c] = f2bf(W[(size_t)(tk + r + 4 * i) * N_ + tn + c]);
    __syncthreads();
#pragma unroll
    for (int i = 0; i < 16; ++i)
        wt[(size_t)(tn + r + 4 * i) * 1024 + tk + c] = tile[c][r + 4 * i];
}

// ---------- init: x fp32 [b][t][k] -> xbf bf16 [t][b][k] ----------
__global__ void k_init_x(const float* __restrict__ x, u16* __restrict__ xbf) {
    size_t e = ((size_t)blockIdx.x * 256 + threadIdx.x) * 8;
    int b = (int)(e >> 18);
    int r = (int)(e & 262143);
    int t = r >> 9, k = r & 511;
    float4 u0 = *(const float4*)(x + e);
    float4 u1 = *(const float4*)(x + e + 4);
    short8v v;
    v[0] = (short)f2bf(u0.x); v[1] = (short)f2bf(u0.y);
    v[2] = (short)f2bf(u0.z); v[3] = (short)f2bf(u0.w);
    v[4] = (short)f2bf(u1.x); v[5] = (short)f2bf(u1.y);
    v[6] = (short)f2bf(u1.z); v[7] = (short)f2bf(u1.w);
    *(short8v*)(xbf + ((size_t)t * B_ + b) * 512 + k) = v;
}

__global__ void k_zero_flags(unsigned* flags) {
    if (threadIdx.x < NWG) flags[threadIdx.x] = 0;
}

// ---------- persistent LN-LSTM ----------
template<bool XBF>
__global__ __launch_bounds__(256, 1)
void k_persist(const float* __restrict__ x, const u16* __restrict__ xbf,
               const u16* __restrict__ wt, const float* __restrict__ bias,
               const float* __restrict__ lnw, const float* __restrict__ lnb,
               const float* __restrict__ hx, const float* __restrict__ cx,
               u16* __restrict__ hbf, float* __restrict__ comb,
               float* __restrict__ statsp, unsigned* __restrict__ flags,
               float* __restrict__ out) {
    __shared__ char wlds[32768];    // 16 cols x 1024 k bf16, XOR-swizzled per col
    __shared__ float sred[4];

    const int tid = threadIdx.x, wgid = blockIdx.x;
    const int n0 = wgid * 16;
    const int w = tid >> 6, l = tid & 63;
    const int rl = l & 15, kg = l >> 4;
    const int row = 16 * w + rl;
    const int row0 = 16 * w + kg * 4;

    // stage W slice into LDS (once, stays for all 512 steps)
    for (int it = 0; it < 8; ++it) {
        int idx = tid + 256 * it;
        int col = idx >> 7, k0 = (idx & 127) * 8;
        short8v v = *(const short8v*)(wt + (size_t)(n0 + col) * 1024 + k0);
        *(short8v*)(wlds + col * 2048 + ((k0 * 2) ^ ((col & 7) << 4))) = v;
    }

    // phase-2 identity
    const int b2 = wgid >> 1;
    const int o = (wgid & 1) * 256 + tid;
    float lw0 = lnw[o], lw1 = lnw[512 + o], lw2 = lnw[1024 + o], lw3 = lnw[1536 + o];
    float lb0 = lnb[o], lb1 = lnb[512 + o], lb2 = lnb[1024 + o], lb3 = lnb[1536 + o];
    float creg = cx[o];
    {   // h init, bf16 pairs, write-through (sc1)
        float h0v = hx[o];
        float hn = __shfl_xor(h0v, 1);
        if (!(tid & 1)) {
            unsigned hp = (unsigned)f2bf(h0v) | ((unsigned)f2bf(hn) << 16);
            __hip_atomic_store((unsigned*)(hbf + b2 * O_ + o), hp,
                               __ATOMIC_RELAXED, __HIP_MEMORY_SCOPE_AGENT);
        }
    }
    const float bcol = bias[n0 + rl];

    // barrier: vmcnt-drain release + relaxed poll + single acquire fence
    auto barrier = [&](unsigned g) {
        asm volatile("s_waitcnt vmcnt(0)" ::: "memory");
        __syncthreads();
        if (tid == 0)
            __hip_atomic_store(flags + wgid, g, __ATOMIC_RELAXED, __HIP_MEMORY_SCOPE_AGENT);
        if (tid < NWG) {
            while (__hip_atomic_load(flags + tid, __ATOMIC_RELAXED,
                                     __HIP_MEMORY_SCOPE_AGENT) < g) {}
        }
        __builtin_amdgcn_fence(__ATOMIC_ACQUIRE, "agent");
        __syncthreads();
    };

    unsigned gen = 1;
    barrier(gen); gen++;

    for (int t = 0; t < T_; ++t) {
        // ============ phase 1: GEMM comb = [x_t | h] @ W + bias ============
        f32x4 a0 = {0.f,0.f,0.f,0.f}, a1 = {0.f,0.f,0.f,0.f};
        f32x4 a2 = {0.f,0.f,0.f,0.f}, a3 = {0.f,0.f,0.f,0.f};
        const u16* hrow = hbf + row * O_;
        const u16* xrowb = XBF ? (xbf + ((size_t)t * B_ + row) * 512) : (const u16*)0;
        const float* xrowf = XBF ? (const float*)0
                                 : (x + (size_t)row * (T_ * 512) + (size_t)t * 512);
#pragma unroll
        for (int kc = 0; kc < 32; ++kc) {
            int kloc = kc * 32 + kg * 8;
            short8v a;
            if (kc < 16) {
                if (XBF) {
                    a = *(const short8v*)(xrowb + kloc);
                } else {
                    float4 u0 = *(const float4*)(xrowf + kloc);
                    float4 u1 = *(const float4*)(xrowf + kloc + 4);
                    a[0] = (short)f2bf(u0.x); a[1] = (short)f2bf(u0.y);
                    a[2] = (short)f2bf(u0.z); a[3] = (short)f2bf(u0.w);
                    a[4] = (short)f2bf(u1.x); a[5] = (short)f2bf(u1.y);
                    a[6] = (short)f2bf(u1.z); a[7] = (short)f2bf(u1.w);
                }
            } else {
                a = *(const short8v*)(hrow + (kloc - 512));
            }
            short8v bb = *(const short8v*)(wlds + rl * 2048 + ((kloc * 2) ^ ((rl & 7) << 4)));
            switch (kc & 3) {
                case 0: a0 = __builtin_amdgcn_mfma_f32_16x16x32_bf16(a, bb, a0, 0, 0, 0); break;
                case 1: a1 = __builtin_amdgcn_mfma_f32_16x16x32_bf16(a, bb, a1, 0, 0, 0); break;
                case 2: a2 = __builtin_amdgcn_mfma_f32_16x16x32_bf16(a, bb, a2, 0, 0, 0); break;
                default: a3 = __builtin_amdgcn_mfma_f32_16x16x32_bf16(a, bb, a3, 0, 0, 0); break;
            }
        }
        f32x4 acc = (a0 + a1) + (a2 + a3);

        // epilogue: +bias, write-through comb, per-row LN partials over 16 cols
        float sj[4], qj[4];
#pragma unroll
        for (int j = 0; j < 4; ++j) {
            float v = acc[j] + bcol;
            __hip_atomic_store(comb + (size_t)(row0 + j) * N_ + (n0 + rl), v,
                               __ATOMIC_RELAXED, __HIP_MEMORY_SCOPE_AGENT);
            sj[j] = v; qj[j] = v * v;
        }
#pragma unroll
        for (int m = 1; m < 16; m <<= 1) {
#pragma unroll
            for (int j = 0; j < 4; ++j) {
                sj[j] += __shfl_xor(sj[j], m);
                qj[j] += __shfl_xor(qj[j], m);
            }
        }
        if (rl == 0) {
#pragma unroll
            for (int j = 0; j < 4; ++j) {
                size_t sidx = ((size_t)(row0 + j) * NWG + wgid) * 2;
                __hip_atomic_store(statsp + sidx, sj[j],
                                   __ATOMIC_RELAXED, __HIP_MEMORY_SCOPE_AGENT);
                __hip_atomic_store(statsp + sidx + 1, qj[j],
                                   __ATOMIC_RELAXED, __HIP_MEMORY_SCOPE_AGENT);
            }
        }

        barrier(gen); gen++;   // comb + stats partials visible

        // ============ phase 2: LN + gates + state update ============
        float s = 0.f, q = 0.f;
        if (tid < NWG) {
            float2 p = *(const float2*)(statsp + ((size_t)b2 * NWG + tid) * 2);
            s = p.x; q = p.y;
        }
#pragma unroll
        for (int m = 32; m > 0; m >>= 1) {
            s += __shfl_down(s, m);
            q += __shfl_down(q, m);
        }
        if (tid < NWG && (tid & 63) == 0) {
            sred[(tid >> 6) * 2] = s;
            sred[(tid >> 6) * 2 + 1] = q;
        }
        __syncthreads();
        float S = sred[0] + sred[2], Q = sred[1] + sred[3];
        float mu = S * (1.0f / 2048.0f);
        float var = Q * (1.0f / 2048.0f) - mu * mu;
        float rstd = rsqrtf(var + EPSF);

        const float* cb = comb + (size_t)b2 * N_ + o;
        float n0v = (cb[0]    - mu) * rstd * lw0 + lb0;
        float n1v = (cb[512]  - mu) * rstd * lw1 + lb1;
        float n2v = (cb[1024] - mu) * rstd * lw2 + lb2;
        float n3v = (cb[1536] - mu) * rstd * lw3 + lb3;
        float ig = 1.f / (1.f + __expf(-n0v));
        float fg = 1.f / (1.f + __expf(-n1v));
        float og = 1.f / (1.f + __expf(-n2v));
        float e2 = __expf(-2.f * fabsf(n3v));
        float th = copysignf((1.f - e2) / (1.f + e2), n3v);
        creg = fg * creg + ig * th;
        float h = og * creg;
        __builtin_nontemporal_store(h, out + (size_t)b2 * (T_ * O_) + (size_t)t * O_ + o);
        float hn = __shfl_xor(h, 1);
        if (!(tid & 1)) {
            unsigned hp = (unsigned)f2bf(h) | ((unsigned)f2bf(hn) << 16);
            __hip_atomic_store((unsigned*)(hbf + b2 * O_ + o), hp,
                               __ATOMIC_RELAXED, __HIP_MEMORY_SCOPE_AGENT);
        }

        barrier(gen); gen++;   // h visible for next step
    }
}

extern "C" void kernel_launch(void* const* d_in, const int* in_sizes, int n_in,
                              void* d_out, int out_size, void* d_ws, size_t ws_size,
                              hipStream_t stream) {
    const float* x    = (const float*)d_in[0];
    const float* W    = (const float*)d_in[1];
    const float* bias = (const float*)d_in[2];
    const float* lnw  = (const float*)d_in[3];
    const float* lnb  = (const float*)d_in[4];
    const float* hx   = (const float*)d_in[5];
    const float* cx   = (const float*)d_in[6];
    float* out = (float*)d_out;

    char* ws = (char*)d_ws;
    u16*     wt     = (u16*)ws;                        // 4 MiB
    u16*     hbf    = (u16*)(ws + 4194304);            // 64 KiB
    float*   comb   = (float*)(ws + 4259840);          // 512 KiB
    float*   statsp = (float*)(ws + 4784128);          // 64 KiB
    unsigned* flags = (unsigned*)(ws + 4849664);       // 512 B
    u16*     xbf    = (u16*)(ws + 5242880);            // 32 MiB (optional)
    bool use_xbf = ws_size >= (5242880u + 33554432u);

    k_init_wt<<<512, 256, 0, stream>>>(W, wt);
    k_zero_flags<<<1, 128, 0, stream>>>(flags);
    if (use_xbf) {
        k_init_x<<<8192, 256, 0, stream>>>(x, xbf);
        k_persist<true><<<NWG, 256, 0, stream>>>(x, xbf, wt, bias, lnw, lnb, hx, cx,
                                                 hbf, comb, statsp, flags, out);
    } else {
        k_persist<false><<<NWG, 256, 0, stream>>>(x, xbf, wt, bias, lnw, lnb, hx, cx,
                                                  hbf, comb, statsp, flags, out);
    }
}

// Round 4
// 5662.022 us; speedup vs baseline: 3.6222x; 1.7296x over previous
//
#include <hip/hip_runtime.h>
#include <hip/hip_bf16.h>

#define B_ 64
#define T_ 512
#define O_ 512
#define N_ 2048
#define NWG 128
#define EPSF 1e-5f

typedef __attribute__((ext_vector_type(8))) short short8v;
typedef __attribute__((ext_vector_type(4))) float f32x4;
typedef unsigned short u16;
typedef unsigned long long u64;

__device__ __forceinline__ u16 f2bf(float f) {
    union { float f; unsigned u; } v; v.f = f;
    unsigned r = v.u + 0x7fffu + ((v.u >> 16) & 1u);   // RNE
    return (u16)(r >> 16);
}

// ---- sc1 (agent-scope, LLC-coherent) access helpers: NO cache-wide fences ----
__device__ __forceinline__ u64 ldg_sc1_u64(const void* p) {
    return __hip_atomic_load((const u64*)p, __ATOMIC_RELAXED, __HIP_MEMORY_SCOPE_AGENT);
}
__device__ __forceinline__ float ldg_sc1_f32(const float* p) {
    return __hip_atomic_load(p, __ATOMIC_RELAXED, __HIP_MEMORY_SCOPE_AGENT);
}
__device__ __forceinline__ void stg_sc1_f32(float* p, float v) {
    __hip_atomic_store(p, v, __ATOMIC_RELAXED, __HIP_MEMORY_SCOPE_AGENT);
}
__device__ __forceinline__ void stg_sc1_u32(unsigned* p, unsigned v) {
    __hip_atomic_store(p, v, __ATOMIC_RELAXED, __HIP_MEMORY_SCOPE_AGENT);
}

// ---------- init: W fp32 [1024][2048] -> wt bf16 [2048 col][1024 k], LDS-tiled ----------
__global__ void k_init_wt(const float* __restrict__ W, u16* __restrict__ wt) {
    __shared__ u16 tile[64][65];
    const int tk = (blockIdx.x >> 5) * 64;
    const int tn = (blockIdx.x & 31) * 64;
    const int r = threadIdx.x >> 6, c = threadIdx.x & 63;
#pragma unroll
    for (int i = 0; i < 16; ++i)
        tile[r + 4 * i][c] = f2bf(W[(size_t)(tk + r + 4 * i) * N_ + tn + c]);
    __syncthreads();
#pragma unroll
    for (int i = 0; i < 16; ++i)
        wt[(size_t)(tn + r + 4 * i) * 1024 + tk + c] = tile[c][r + 4 * i];
}

// ---------- init: x fp32 [b][t][k] -> xbf bf16 [t][b][k] ----------
__global__ void k_init_x(const float* __restrict__ x, u16* __restrict__ xbf) {
    size_t e = ((size_t)blockIdx.x * 256 + threadIdx.x) * 8;
    int b = (int)(e >> 18);
    int r = (int)(e & 262143);
    int t = r >> 9, k = r & 511;
    float4 u0 = *(const float4*)(x + e);
    float4 u1 = *(const float4*)(x + e + 4);
    short8v v;
    v[0] = (short)f2bf(u0.x); v[1] = (short)f2bf(u0.y);
    v[2] = (short)f2bf(u0.z); v[3] = (short)f2bf(u0.w);
    v[4] = (short)f2bf(u1.x); v[5] = (short)f2bf(u1.y);
    v[6] = (short)f2bf(u1.z); v[7] = (short)f2bf(u1.w);
    *(short8v*)(xbf + ((size_t)t * B_ + b) * 512 + k) = v;
}

__global__ void k_zero_flags(unsigned* flags) {
    stg_sc1_u32(flags + threadIdx.x, 0u);   // 256 entries (flags[0..127], go at [128])
}

// ---------- persistent LN-LSTM ----------
template<bool XBF>
__global__ __launch_bounds__(256, 1)
void k_persist(const float* __restrict__ x, const u16* __restrict__ xbf,
               const u16* __restrict__ wt, const float* __restrict__ bias,
               const float* __restrict__ lnw, const float* __restrict__ lnb,
               const float* __restrict__ hx, const float* __restrict__ cx,
               u16* __restrict__ hbf, float* __restrict__ comb,
               float* __restrict__ statsp, unsigned* __restrict__ flags,
               float* __restrict__ out) {
    __shared__ char wlds[32768];    // 16 cols x 1024 k bf16, XOR-swizzled
    __shared__ float sred[4];
    unsigned* go = flags + NWG;

    const int tid = threadIdx.x, wgid = blockIdx.x;
    const int n0 = wgid * 16;
    const int w = tid >> 6, l = tid & 63;
    const int rl = l & 15, kg = l >> 4;
    const int row = 16 * w + rl;
    const int row0 = 16 * w + kg * 4;

    // stage W slice into LDS (once)
    for (int it = 0; it < 8; ++it) {
        int idx = tid + 256 * it;
        int col = idx >> 7, k0 = (idx & 127) * 8;
        short8v v = *(const short8v*)(wt + (size_t)(n0 + col) * 1024 + k0);
        *(short8v*)(wlds + col * 2048 + ((k0 * 2) ^ ((col & 7) << 4))) = v;
    }

    // phase-2 identity
    const int b2 = wgid >> 1;
    const int o = (wgid & 1) * 256 + tid;
    float lw0 = lnw[o], lw1 = lnw[512 + o], lw2 = lnw[1024 + o], lw3 = lnw[1536 + o];
    float lb0 = lnb[o], lb1 = lnb[512 + o], lb2 = lnb[1024 + o], lb3 = lnb[1536 + o];
    float creg = cx[o];
    {
        float h0v = hx[o];
        float hn = __shfl_xor(h0v, 1);
        if (!(tid & 1)) {
            unsigned hp = (unsigned)f2bf(h0v) | ((unsigned)f2bf(hn) << 16);
            stg_sc1_u32((unsigned*)(hbf + b2 * O_ + o), hp);
        }
    }
    const float bcol = bias[n0 + rl];

    // ---- barrier: parallel flag stores + single aggregator + single go word ----
    auto arrive = [&](unsigned g) {
        asm volatile("s_waitcnt vmcnt(0)" ::: "memory");   // sc1 stores at LLC
        __syncthreads();
        if (tid == 0) stg_sc1_u32(flags + wgid, g);
    };
    auto wait = [&](unsigned g) {
        if (wgid == 0) {
            if (tid < NWG)
                while (__hip_atomic_load(flags + tid, __ATOMIC_RELAXED,
                                         __HIP_MEMORY_SCOPE_AGENT) < g) {}
            __syncthreads();
            if (tid == 0) stg_sc1_u32(go, g);
        } else {
            if (tid == 0)
                while (__hip_atomic_load(go, __ATOMIC_RELAXED,
                                         __HIP_MEMORY_SCOPE_AGENT) < g) {}
            __syncthreads();
        }
    };

    // GEMM halves
    auto xhalf = [&](int t, f32x4& c0, f32x4& c1) {
        const u16* xrowb = XBF ? (xbf + ((size_t)t * B_ + row) * 512) : (const u16*)0;
        const float* xrowf = XBF ? (const float*)0
                                 : (x + (size_t)row * (T_ * 512) + (size_t)t * 512);
#pragma unroll
        for (int kc = 0; kc < 16; ++kc) {
            int kloc = kc * 32 + kg * 8;
            short8v a;
            if (XBF) {
                a = *(const short8v*)(xrowb + kloc);
            } else {
                float4 u0 = *(const float4*)(xrowf + kloc);
                float4 u1 = *(const float4*)(xrowf + kloc + 4);
                a[0] = (short)f2bf(u0.x); a[1] = (short)f2bf(u0.y);
                a[2] = (short)f2bf(u0.z); a[3] = (short)f2bf(u0.w);
                a[4] = (short)f2bf(u1.x); a[5] = (short)f2bf(u1.y);
                a[6] = (short)f2bf(u1.z); a[7] = (short)f2bf(u1.w);
            }
            short8v bb = *(const short8v*)(wlds + rl * 2048 + ((kloc * 2) ^ ((rl & 7) << 4)));
            if (kc & 1) c1 = __builtin_amdgcn_mfma_f32_16x16x32_bf16(a, bb, c1, 0, 0, 0);
            else        c0 = __builtin_amdgcn_mfma_f32_16x16x32_bf16(a, bb, c0, 0, 0, 0);
        }
    };
    auto hhalf = [&](f32x4& c0, f32x4& c1) {
        const u16* hrow = hbf + row * O_;
#pragma unroll
        for (int kc = 0; kc < 16; ++kc) {
            int kloc = kc * 32 + kg * 8;          // 0..511 within h
            union { u64 q[2]; short8v v; } u;
            u.q[0] = ldg_sc1_u64(hrow + kloc);    // h always fresh at LLC: no inv needed
            u.q[1] = ldg_sc1_u64(hrow + kloc + 4);
            short8v bb = *(const short8v*)(wlds + rl * 2048 +
                           (((kloc + 512) * 2) ^ ((rl & 7) << 4)));
            if (kc & 1) c1 = __builtin_amdgcn_mfma_f32_16x16x32_bf16(u.v, bb, c1, 0, 0, 0);
            else        c0 = __builtin_amdgcn_mfma_f32_16x16x32_bf16(u.v, bb, c0, 0, 0, 0);
        }
    };

    unsigned gen = 1;
    arrive(gen); wait(gen); gen++;     // wlds + hbf init visible

    f32x4 xa0 = {0.f,0.f,0.f,0.f}, xa1 = {0.f,0.f,0.f,0.f};
    xhalf(0, xa0, xa1);

    for (int t = 0; t < T_; ++t) {
        // ============ phase 1: finish GEMM with h-half ============
        f32x4 ha0 = {0.f,0.f,0.f,0.f}, ha1 = {0.f,0.f,0.f,0.f};
        hhalf(ha0, ha1);
        f32x4 acc = (xa0 + xa1) + (ha0 + ha1);

        float sj[4], qj[4];
#pragma unroll
        for (int j = 0; j < 4; ++j) {
            float v = acc[j] + bcol;
            stg_sc1_f32(comb + (size_t)(row0 + j) * N_ + (n0 + rl), v);
            sj[j] = v; qj[j] = v * v;
        }
#pragma unroll
        for (int m = 1; m < 16; m <<= 1) {
#pragma unroll
            for (int j = 0; j < 4; ++j) {
                sj[j] += __shfl_xor(sj[j], m);
                qj[j] += __shfl_xor(qj[j], m);
            }
        }
        if (rl == 0) {
#pragma unroll
            for (int j = 0; j < 4; ++j) {
                size_t sidx = ((size_t)(row0 + j) * NWG + wgid) * 2;
                stg_sc1_f32(statsp + sidx, sj[j]);
                stg_sc1_f32(statsp + sidx + 1, qj[j]);
            }
        }

        arrive(gen); wait(gen); gen++;     // comb + stats visible (at LLC)

        // ============ phase 2: LN + gates + state update ============
        float s = 0.f, q = 0.f;
        if (tid < NWG) {
            union { u64 q64; float f[2]; } p;
            p.q64 = ldg_sc1_u64(statsp + ((size_t)b2 * NWG + tid) * 2);
            s = p.f[0]; q = p.f[1];
        }
#pragma unroll
        for (int m = 32; m > 0; m >>= 1) {
            s += __shfl_down(s, m);
            q += __shfl_down(q, m);
        }
        if (tid < NWG && (tid & 63) == 0) {
            sred[(tid >> 6) * 2] = s;
            sred[(tid >> 6) * 2 + 1] = q;
        }
        __syncthreads();
        float S = sred[0] + sred[2], Q = sred[1] + sred[3];
        float mu = S * (1.0f / 2048.0f);
        float var = Q * (1.0f / 2048.0f) - mu * mu;
        float rstd = rsqrtf(var + EPSF);

        const float* cb = comb + (size_t)b2 * N_ + o;
        float n0v = (ldg_sc1_f32(cb)        - mu) * rstd * lw0 + lb0;
        float n1v = (ldg_sc1_f32(cb + 512)  - mu) * rstd * lw1 + lb1;
        float n2v = (ldg_sc1_f32(cb + 1024) - mu) * rstd * lw2 + lb2;
        float n3v = (ldg_sc1_f32(cb + 1536) - mu) * rstd * lw3 + lb3;
        float ig = 1.f / (1.f + __expf(-n0v));
        float fg = 1.f / (1.f + __expf(-n1v));
        float og = 1.f / (1.f + __expf(-n2v));
        float e2 = __expf(-2.f * fabsf(n3v));
        float th = copysignf((1.f - e2) / (1.f + e2), n3v);
        creg = fg * creg + ig * th;
        float h = og * creg;
        __builtin_nontemporal_store(h, out + (size_t)b2 * (T_ * O_) + (size_t)t * O_ + o);
        float hn = __shfl_xor(h, 1);
        if (!(tid & 1)) {
            unsigned hp = (unsigned)f2bf(h) | ((unsigned)f2bf(hn) << 16);
            stg_sc1_u32((unsigned*)(hbf + b2 * O_ + o), hp);
        }

        if (t == T_ - 1) break;            // no one consumes the last h

        arrive(gen);
        // overlap the go-propagation with next step's h-independent GEMM half
        xa0 = f32x4{0.f,0.f,0.f,0.f}; xa1 = f32x4{0.f,0.f,0.f,0.f};
        xhalf(t + 1, xa0, xa1);
        wait(gen); gen++;                  // h visible
    }
}

extern "C" void kernel_launch(void* const* d_in, const int* in_sizes, int n_in,
                              void* d_out, int out_size, void* d_ws, size_t ws_size,
                              hipStream_t stream) {
    const float* x    = (const float*)d_in[0];
    const float* W    = (const float*)d_in[1];
    const float* bias = (const float*)d_in[2];
    const float* lnw  = (const float*)d_in[3];
    const float* lnb  = (const float*)d_in[4];
    const float* hx   = (const float*)d_in[5];
    const float* cx   = (const float*)d_in[6];
    float* out = (float*)d_out;

    char* ws = (char*)d_ws;
    u16*     wt     = (u16*)ws;                        // 4 MiB
    u16*     hbf    = (u16*)(ws + 4194304);            // 64 KiB
    float*   comb   = (float*)(ws + 4259840);          // 512 KiB
    float*   statsp = (float*)(ws + 4784128);          // 128 KiB
    unsigned* flags = (unsigned*)(ws + 4915200);       // 1 KiB
    u16*     xbf    = (u16*)(ws + 5242880);            // 32 MiB (optional)
    bool use_xbf = ws_size >= (5242880u + 33554432u);

    k_init_wt<<<512, 256, 0, stream>>>(W, wt);
    k_zero_flags<<<1, 256, 0, stream>>>(flags);
    if (use_xbf) {
        k_init_x<<<8192, 256, 0, stream>>>(x, xbf);
        k_persist<true><<<NWG, 256, 0, stream>>>(x, xbf, wt, bias, lnw, lnb, hx, cx,
                                                 hbf, comb, statsp, flags, out);
    } else {
        k_persist<false><<<NWG, 256, 0, stream>>>(x, xbf, wt, bias, lnw, lnb, hx, cx,
                                                  hbf, comb, statsp, flags, out);
    }
}